// Round 9
// baseline (219.350 us; speedup 1.0000x reference)
//
#include <hip/hip_runtime.h>

// out[b, 2n+o] = x[b,2n]*W[n,0,o] + x[b,2n+1]*W[n,1,o]
// W[n,m,o] = softmax_m(c[n,:,o]) = sigmoid(c[n,m,o] - c[n,1-m,o])
// Pure streaming (x read once 512 MiB, out written once 512 MiB), fp32.
//
// R8 (2-stage reg pipeline, nt/nt) = 209.4us (5.13 TB/s). Residual theory:
// single in-order vmcnt queue mixes loads+stores -> every load-wait drains
// older store-acks. This round: producer/consumer WAVE SPLIT so no wave ever
// has loads and stores in the same vmcnt queue.
//   waves 0-1 (producer): global_load_lds x -> LDS (vmcnt = loads only)
//   waves 2-3 (consumer): ds_read_b128 -> 8 FMA -> nt store (vmcnt = stores only)
// Double-buffered 2x16KB LDS, 1 __syncthreads per phase (its vmcnt(0) drain IS
// the producer's publish). 5 blocks/CU (160KB LDS), 20 waves/CU.
#define NCHUNK4   2048   // f32x4 per row
#define STRIPW    256    // f32x4 strip per block (4KB/row)
#define NSTRIPS   8
#define ROWSPG    64     // rows per block
#define PHROWS    4      // rows per phase
#define NPHASE    (ROWSPG / PHROWS)   // 16
#define PHCH      (PHROWS * STRIPW)   // 1024 f32x4 = 16KB per buffer

typedef float f32x4 __attribute__((ext_vector_type(4)));

__device__ __forceinline__ void gload_lds16(const float* g, void* l) {
    __builtin_amdgcn_global_load_lds(
        (const __attribute__((address_space(1))) void*)g,
        (__attribute__((address_space(3))) void*)l, 16, 0, 0);
}

__global__ __launch_bounds__(256, 5)
void EfficientLearnableInterconnect_33913061769291_kernel(
        const float* __restrict__ x,
        const float* __restrict__ c,
        float* __restrict__ out) {
    __shared__ f32x4 buf[2][PHCH];   // 32 KiB

    const int strip = blockIdx.x & (NSTRIPS - 1);
    const int rowg  = blockIdx.x >> 3;
    const int row0  = rowg * ROWSPG;
    const int tid   = threadIdx.x;
    const bool producer = tid < 128;

    // ---- consumer-only setup: 2 weight sets (cols q and q+128 of the strip)
    float wA[8], wB[8];
    const int q = tid & 127;
    if (!producer) {
        const f32x4* c4 = (const f32x4*)c;
        #pragma unroll 2
        for (int s = 0; s < 2; ++s) {
            const int col4 = strip * STRIPW + s * 128 + q;
            const f32x4 c0 = c4[2 * col4];
            const f32x4 c1 = c4[2 * col4 + 1];
            float* W = s ? wB : wA;
            W[0] = 1.f / (1.f + __expf(c0.z - c0.x));  // w000
            W[1] = 1.f / (1.f + __expf(c0.x - c0.z));  // w010
            W[2] = 1.f / (1.f + __expf(c0.w - c0.y));  // w001
            W[3] = 1.f / (1.f + __expf(c0.y - c0.w));  // w011
            W[4] = 1.f / (1.f + __expf(c1.z - c1.x));  // w100
            W[5] = 1.f / (1.f + __expf(c1.x - c1.z));  // w110
            W[6] = 1.f / (1.f + __expf(c1.w - c1.y));  // w101
            W[7] = 1.f / (1.f + __expf(c1.y - c1.w));  // w111
        }
    }

    // ---- producer lambda: stage PHROWS rows of this strip into buf[p&1]
    const int w    = tid >> 6;   // producer wave 0/1
    const int lane = tid & 63;
    auto issue = [&](int p) {
        const int pb = p & 1;
        const float* gb = x + ((size_t)(row0 + p * PHROWS) * NCHUNK4 + strip * STRIPW) * 4;
        // flat f32x4 index within phase: f = i*128 + w*64 + lane
        //   row = i>>1, col-in-strip = (i&1)*128 + w*64 + lane
        #pragma unroll
        for (int i = 0; i < 8; ++i) {
            const float* g = gb +
                ((size_t)(i >> 1) * NCHUNK4 + ((i & 1) * 128 + w * 64 + lane)) * 4;
            // LDS dest: wave-uniform base; HW deposits base + lane*16 (linear)
            gload_lds16(g, (void*)&buf[pb][i * 128 + w * 64]);
        }
    };

    if (producer) issue(0);
    __syncthreads();   // vmcnt(0) drain publishes buf[0]

    for (int p = 0; p < NPHASE; ++p) {
        if (producer) {
            if (p + 1 < NPHASE) issue(p + 1);   // fill buf[(p+1)&1]
        } else {
            const int pb = p & 1;
            f32x4 v[8];
            #pragma unroll
            for (int j = 0; j < 8; ++j)
                v[j] = buf[pb][j * 128 + q];
            #pragma unroll
            for (int j = 0; j < 8; ++j) {
                const float* W = (j & 1) ? wB : wA;   // static after unroll
                f32x4 o;
                o.x = v[j].x * W[0] + v[j].y * W[1];
                o.y = v[j].x * W[2] + v[j].y * W[3];
                o.z = v[j].z * W[4] + v[j].w * W[5];
                o.w = v[j].z * W[6] + v[j].w * W[7];
                const size_t oi = (size_t)(row0 + p * PHROWS + (j >> 1)) * NCHUNK4
                                + strip * STRIPW + (j & 1) * 128 + q;
                __builtin_nontemporal_store(o, (f32x4*)out + oi);
            }
        }
        __syncthreads();   // producer: vmcnt(0) = publish; consumer: reads done
    }
}

extern "C" void kernel_launch(void* const* d_in, const int* in_sizes, int n_in,
                              void* d_out, int out_size, void* d_ws, size_t ws_size,
                              hipStream_t stream) {
    const float* x = (const float*)d_in[0];
    const float* c = (const float*)d_in[1];
    float* out = (float*)d_out;

    const dim3 grid(NSTRIPS * (16384 / ROWSPG));  // 2048 blocks
    const dim3 block(256);
    EfficientLearnableInterconnect_33913061769291_kernel<<<grid, block, 0, stream>>>(x, c, out);
}

// Round 10
// 187.134 us; speedup vs baseline: 1.1722x; 1.1722x over previous
//
#include <hip/hip_runtime.h>

// out[b, 2n+o] = x[b,2n]*W[n,0,o] + x[b,2n+1]*W[n,1,o]
// W[n,m,o] = softmax_m(c[n,:,o]) = sigmoid(c[n,m,o] - c[n,1-m,o])
// Pure streaming: x read once (512 MiB), out written once (512 MiB), fp32.
//
// R8 (2-stage reg pipeline, nt/nt, 256thr) = 209.4us / 5.13 TB/s = best.
// R9 (producer/consumer, directions ANTI-aligned) = 219.4 — worse. Theory:
// HBM DQ-bus turnaround penalizes fine-grained read/write interleave; the
// remaining software lever is temporal direction-batching. This round: R8's
// exact schedule, but 1024-thread blocks (16 waves, 2 blocks/CU -> still 32
// waves/CU) with RAW s_barrier (no vmcnt drain!) between load-batch and
// store-batch phases, so 16 waves issue loads together, then stores together.
#define ELI_NCHUNK    2048                   // f32x4 per row
#define ELI_ROWS_PG   64                     // rows per thread

typedef float f32x4 __attribute__((ext_vector_type(4)));

#define NTL(p)     __builtin_nontemporal_load(p)
#define NTS(p, v)  __builtin_nontemporal_store((v), (p))
// raw barrier: compiler memory fence + s_barrier, NO s_waitcnt vmcnt(0) drain
#define PHASE_BAR() do { asm volatile("" ::: "memory"); \
                         __builtin_amdgcn_s_barrier();  \
                         asm volatile("" ::: "memory"); } while (0)

__global__ __launch_bounds__(1024, 8)
void EfficientLearnableInterconnect_33913061769291_kernel(
        const float* __restrict__ x,
        const float* __restrict__ c,
        float* __restrict__ out) {
    // treat each 256-thread quarter as one R8-block
    const int tq   = threadIdx.x >> 8;              // quarter 0..3
    const int t    = threadIdx.x & 255;
    const int vblk = blockIdx.x * 4 + tq;           // 0..2047
    const int strip = vblk & 7;
    const int rowg  = vblk >> 3;
    const int chunk = strip * 256 + t;              // 0..2047
    const int row0  = rowg * ELI_ROWS_PG;

    // c[n] as f32x4: (c[n,0,0], c[n,0,1], c[n,1,0], c[n,1,1])
    const f32x4 c0 = ((const f32x4*)c)[2 * chunk];
    const f32x4 c1 = ((const f32x4*)c)[2 * chunk + 1];

    const float w000 = 1.f / (1.f + __expf(c0.z - c0.x));
    const float w010 = 1.f / (1.f + __expf(c0.x - c0.z));
    const float w001 = 1.f / (1.f + __expf(c0.w - c0.y));
    const float w011 = 1.f / (1.f + __expf(c0.y - c0.w));
    const float w100 = 1.f / (1.f + __expf(c1.z - c1.x));
    const float w110 = 1.f / (1.f + __expf(c1.x - c1.z));
    const float w101 = 1.f / (1.f + __expf(c1.w - c1.y));
    const float w111 = 1.f / (1.f + __expf(c1.y - c1.w));

#define APPLY(v) ({ f32x4 _o; \
    _o.x = (v).x * w000 + (v).y * w010; \
    _o.y = (v).x * w001 + (v).y * w011; \
    _o.z = (v).z * w100 + (v).w * w110; \
    _o.w = (v).z * w101 + (v).w * w111; _o; })

    const f32x4* __restrict__ xp = (const f32x4*)x + (size_t)row0 * ELI_NCHUNK + chunk;
    f32x4* __restrict__       op = (f32x4*)out     + (size_t)row0 * ELI_NCHUNK + chunk;

    f32x4 va0, va1, va2, va3, vb0, vb1, vb2, vb3;

    // prologue: rows 0..3
    va0 = NTL(xp + 0 * ELI_NCHUNK);
    va1 = NTL(xp + 1 * ELI_NCHUNK);
    va2 = NTL(xp + 2 * ELI_NCHUNK);
    va3 = NTL(xp + 3 * ELI_NCHUNK);

    for (int g = 0; g < 7; ++g) {
        // LOAD phase: rows +4..7
        vb0 = NTL(xp + 4 * ELI_NCHUNK);
        vb1 = NTL(xp + 5 * ELI_NCHUNK);
        vb2 = NTL(xp + 6 * ELI_NCHUNK);
        vb3 = NTL(xp + 7 * ELI_NCHUNK);
        PHASE_BAR();               // align 16 waves: switch to store phase
        // STORE phase: rows +0..3
        NTS(op + 0 * ELI_NCHUNK, APPLY(va0));
        NTS(op + 1 * ELI_NCHUNK, APPLY(va1));
        NTS(op + 2 * ELI_NCHUNK, APPLY(va2));
        NTS(op + 3 * ELI_NCHUNK, APPLY(va3));
        // LOAD phase: rows +8..11
        va0 = NTL(xp + 8  * ELI_NCHUNK);
        va1 = NTL(xp + 9  * ELI_NCHUNK);
        va2 = NTL(xp + 10 * ELI_NCHUNK);
        va3 = NTL(xp + 11 * ELI_NCHUNK);
        PHASE_BAR();               // align: switch to store phase
        // STORE phase: rows +4..7
        NTS(op + 4 * ELI_NCHUNK, APPLY(vb0));
        NTS(op + 5 * ELI_NCHUNK, APPLY(vb1));
        NTS(op + 6 * ELI_NCHUNK, APPLY(vb2));
        NTS(op + 7 * ELI_NCHUNK, APPLY(vb3));
        xp += 8 * ELI_NCHUNK;
        op += 8 * ELI_NCHUNK;
    }
    // epilogue: rows 56..63 (xp/op at row 56)
    vb0 = NTL(xp + 4 * ELI_NCHUNK);
    vb1 = NTL(xp + 5 * ELI_NCHUNK);
    vb2 = NTL(xp + 6 * ELI_NCHUNK);
    vb3 = NTL(xp + 7 * ELI_NCHUNK);
    NTS(op + 0 * ELI_NCHUNK, APPLY(va0));
    NTS(op + 1 * ELI_NCHUNK, APPLY(va1));
    NTS(op + 2 * ELI_NCHUNK, APPLY(va2));
    NTS(op + 3 * ELI_NCHUNK, APPLY(va3));
    NTS(op + 4 * ELI_NCHUNK, APPLY(vb0));
    NTS(op + 5 * ELI_NCHUNK, APPLY(vb1));
    NTS(op + 6 * ELI_NCHUNK, APPLY(vb2));
    NTS(op + 7 * ELI_NCHUNK, APPLY(vb3));
#undef APPLY
}

extern "C" void kernel_launch(void* const* d_in, const int* in_sizes, int n_in,
                              void* d_out, int out_size, void* d_ws, size_t ws_size,
                              hipStream_t stream) {
    const float* x = (const float*)d_in[0];
    const float* c = (const float*)d_in[1];
    float* out = (float*)d_out;

    const dim3 grid(512);     // 512 x 1024thr = 2048 virtual R8-blocks
    const dim3 block(1024);
    EfficientLearnableInterconnect_33913061769291_kernel<<<grid, block, 0, stream>>>(x, c, out);
}